// Round 1
// baseline (218.182 us; speedup 1.0000x reference)
//
#include <hip/hip_runtime.h>
#include <hip/hip_bf16.h>

#define N_NODES 100000
#define N_EDGES 1600000
#define IN_F 128
#define OUT_F 32

// ---------------- GEMM: support[N,32] = x[N,128] @ W[128,32] ----------------
// 256 threads = 8 rows x 32 output-features. W fully staged in LDS (16 KB),
// 8 x-rows staged in LDS (4 KB) via coalesced float4 loads.
__global__ __launch_bounds__(256) void gcn_gemm_kernel(
    const float* __restrict__ x, const float* __restrict__ w,
    float* __restrict__ support) {
  __shared__ float wlds[IN_F][OUT_F];  // 16 KB, same row-major layout as W
  __shared__ float xlds[8][IN_F];      // 4 KB
  const int tid = threadIdx.x;
  const int row0 = blockIdx.x * 8;

  // Load W: 4096 floats = 1024 float4, 256 threads -> 4 each.
  {
    const float4* wsrc = (const float4*)w;
    float4* wdst = (float4*)&wlds[0][0];
    #pragma unroll
    for (int i = 0; i < 4; ++i) wdst[tid + i * 256] = wsrc[tid + i * 256];
  }
  // Load 8 rows of x: 1024 floats = 256 float4, one per thread. Coalesced.
  {
    const int r = tid >> 5;       // 0..7
    const int c4 = tid & 31;      // float4 index within row
    const int row = row0 + r;
    float4 v = make_float4(0.f, 0.f, 0.f, 0.f);
    if (row < N_NODES) v = ((const float4*)(x + (size_t)row * IN_F))[c4];
    ((float4*)&xlds[r][0])[c4] = v;
  }
  __syncthreads();

  const int f = tid & 31;   // output feature
  const int r = tid >> 5;   // row within block
  const int row = row0 + r;
  float acc = 0.f;
  #pragma unroll
  for (int k = 0; k < IN_F; ++k) acc += xlds[r][k] * wlds[k][f];
  if (row < N_NODES) support[(size_t)row * OUT_F + f] = acc;
}

// ---------------- out init: out[n,f] = bias[f] ----------------
__global__ __launch_bounds__(256) void gcn_init_out_kernel(
    float* __restrict__ out, const float* __restrict__ bias) {
  const int i = blockIdx.x * 256 + threadIdx.x;
  if (i < N_NODES * OUT_F) out[i] = bias[i & (OUT_F - 1)];
}

// ---------------- scatter: out[row[e],f] += val[e] * support[col[e],f] ------
// One thread per (edge, feature). Lanes 0..31 of each 32-lane group share an
// edge: index/val loads are same-address broadcasts; support gather and the
// atomic destinations are 128B-contiguous per group.
__global__ __launch_bounds__(256) void gcn_scatter_kernel(
    const float* __restrict__ support, const int* __restrict__ erow,
    const int* __restrict__ ecol, const float* __restrict__ eval,
    float* __restrict__ out) {
  const long long idx = (long long)blockIdx.x * 256 + threadIdx.x;
  if (idx >= (long long)N_EDGES * OUT_F) return;
  const int e = (int)(idx >> 5);
  const int f = (int)(idx & 31);
  const float v = eval[e];
  const int c = ecol[e];
  const int r = erow[e];
  atomicAdd(&out[(size_t)r * OUT_F + f], v * support[(size_t)c * OUT_F + f]);
}

extern "C" void kernel_launch(void* const* d_in, const int* in_sizes, int n_in,
                              void* d_out, int out_size, void* d_ws, size_t ws_size,
                              hipStream_t stream) {
  const float* x = (const float*)d_in[0];
  const int* erow = (const int*)d_in[1];
  const int* ecol = (const int*)d_in[2];
  const float* eval = (const float*)d_in[3];
  const float* w = (const float*)d_in[4];
  const float* bias = (const float*)d_in[5];
  float* out = (float*)d_out;
  float* support = (float*)d_ws;  // N_NODES * OUT_F floats = 12.8 MB

  // 1) support = x @ W
  gcn_gemm_kernel<<<(N_NODES + 7) / 8, 256, 0, stream>>>(x, w, support);
  // 2) out = bias (broadcast)
  gcn_init_out_kernel<<<(N_NODES * OUT_F + 255) / 256, 256, 0, stream>>>(out, bias);
  // 3) scatter-add edges
  const long long total = (long long)N_EDGES * OUT_F;
  gcn_scatter_kernel<<<(int)((total + 255) / 256), 256, 0, stream>>>(
      support, erow, ecol, eval, out);
}